// Round 3
// baseline (47.894 us; speedup 1.0000x reference)
//
#include <hip/hip_runtime.h>
#include <hip/hip_bf16.h>

#define C_IN 1024
#define T_SZ 128
#define CTX 64
#define NEV 16
#define BK 32
#define NTILE 32    // C_IN / BK
#define NBUF 4
#define NTHR 512
#define WBROW 40    // padded bf16 W row stride (elems) -> 80 B
#define PLROW 132   // padded P dump row stride (f32 elems)

typedef short bf16x8 __attribute__((ext_vector_type(8)));
typedef float f32x4 __attribute__((ext_vector_type(4)));

__device__ __forceinline__ unsigned short f2bf(float f) {
  __hip_bfloat16 h = __float2bfloat16(f);
  return *(unsigned short*)&h;
}

#define WAITVM(N) asm volatile("s_waitcnt vmcnt(" #N ")" ::: "memory")
#define WAITLG()  asm volatile("s_waitcnt lgkmcnt(0)" ::: "memory")
#define SCHED0()  __builtin_amdgcn_sched_barrier(0)

#define GLD16(gp, lp) __builtin_amdgcn_global_load_lds( \
    (const __attribute__((address_space(1))) unsigned int*)(gp), \
    (__attribute__((address_space(3))) unsigned int*)(lp), 16, 0, 0)
#define GLD4(gp, lp) __builtin_amdgcn_global_load_lds( \
    (const __attribute__((address_space(1))) unsigned int*)(gp), \
    (__attribute__((address_space(3))) unsigned int*)(lp), 4, 0, 0)

__global__ __launch_bounds__(NTHR, 1) void fused_sparsify(
    const float* __restrict__ enc,   // [256][1024][128] f32
    const float* __restrict__ wvec,  // [64][1024] f32
    const float* __restrict__ bvec,  // [64] f32
    const float* __restrict__ wsw,   // [1024] f32
    const float* __restrict__ bsw,   // [1] f32
    float* __restrict__ out)         // vecs [256*16*64] ++ sched [256*16*128], f32
{
  const int b    = blockIdx.x;
  const int tid  = threadIdx.x;
  const int lane = tid & 63;
  const int wv   = tid >> 6;   // wave 0..7
  const int g    = lane >> 4;  // k-group 0..3
  const int tl   = lane & 15;
  const int n0   = wv * 16;    // this wave's t-slice

  __shared__ float encb[NBUF][BK][T_SZ];        // 64 KB linear ring (gload_lds dest)
  __shared__ float Wf[NBUF][CTX][BK];           // 32 KB f32 W ring (gload_lds dest)
  __shared__ unsigned short Wbf[2][CTX][WBROW]; // 10 KB bf16 W ping-pong
  __shared__ float wswl[C_IN];                  // 4 KB
  __shared__ float swpart[NTHR];                // 2 KB
  __shared__ float attn[T_SZ];
  __shared__ float topv[NEV];
  __shared__ int   topi[NEV];

  const float* encB = enc + (size_t)b * (C_IN * T_SZ);

  // per-thread staging geometry
  const int wd = tid >> 3;            // W row 0..63
  const int wc = (tid & 7) * 4;       // W col (4 f32 per thread)

  // ---------- prologue ----------
  // issue order (oldest->youngest) must satisfy: W(k+1) older than E(k)
  GLD4(wsw + tid,       &wswl[0] + tid);
  GLD4(wsw + 512 + tid, &wswl[0] + 512 + tid);
  GLD16(wvec + wd * C_IN + 0 * BK + wc, &Wf[0][0][0] + tid * 4);   // W0
  GLD16(wvec + wd * C_IN + 1 * BK + wc, &Wf[1][0][0] + tid * 4);   // W1
  {
    int e0 = tid * 4, e1 = (512 + tid) * 4;
    GLD16(encB + 0 * 4096 + e0, &encb[0][0][0] + e0);              // E0
    GLD16(encB + 0 * 4096 + e1, &encb[0][0][0] + e1);
    GLD16(wvec + wd * C_IN + 2 * BK + wc, &Wf[2][0][0] + tid * 4); // W2
    GLD16(encB + 1 * 4096 + e0, &encb[1][0][0] + e0);              // E1
    GLD16(encB + 1 * 4096 + e1, &encb[1][0][0] + e1);
    GLD16(wvec + wd * C_IN + 3 * BK + wc, &Wf[3][0][0] + tid * 4); // W3
    GLD16(encB + 2 * 4096 + e0, &encb[2][0][0] + e0);              // E2
    GLD16(encB + 2 * 4096 + e1, &encb[2][0][0] + e1);
  }
  WAITVM(9);   // completes wswl(2) + W0(1); 9 left in flight
  SCHED0();
  {  // convert W0 -> Wbf[0] (each thread converts what it staged)
    f32x4 w = *(const f32x4*)(&Wf[0][0][0] + tid * 4);
    union { unsigned long long u; unsigned short s[4]; } pk;
    pk.s[0] = f2bf(w[0]); pk.s[1] = f2bf(w[1]); pk.s[2] = f2bf(w[2]); pk.s[3] = f2bf(w[3]);
    *(unsigned long long*)&Wbf[0][wd][wc] = pk.u;
  }
  WAITLG();
  __builtin_amdgcn_s_barrier();
  SCHED0();

  f32x4 acc0 = {0.f, 0.f, 0.f, 0.f};
  f32x4 acc1 = acc0, acc2 = acc0, acc3 = acc0;
  float sw_acc = 0.f;

  // ---------- main loop: {wait; barrier; issue; convert W(t+1); compute(t)} ----------
#pragma unroll 1
  for (int t = 0; t < NTILE; ++t) {
    if (t < 29)      { WAITVM(6); }  // completes W(t+1) + E(t); ~2.5 tiles stay in flight
    else if (t == 29){ WAITVM(5); }
    else if (t == 30){ WAITVM(2); }
    else             { WAITVM(0); }
    SCHED0();
    WAITLG();
    __builtin_amdgcn_s_barrier();
    SCHED0();

    // issue next-next staging (slots 3..4 ahead of any live reader)
    if (t + 4 < NTILE) {
      GLD16(wvec + wd * C_IN + (t + 4) * BK + wc, &Wf[(t + 4) & 3][0][0] + tid * 4);
    }
    if (t + 3 < NTILE) {
      const float* gsrc = encB + (t + 3) * 4096;
      float* ldst = &encb[(t + 3) & 3][0][0];
      int e0 = tid * 4, e1 = (512 + tid) * 4;
      GLD16(gsrc + e0, ldst + e0);
      GLD16(gsrc + e1, ldst + e1);
    }

    // convert W(t+1) f32 -> bf16 ping-pong (self-staged elems; publish via next barrier)
    if (t + 1 < NTILE) {
      f32x4 w = *(const f32x4*)(&Wf[(t + 1) & 3][0][0] + tid * 4);
      union { unsigned long long u; unsigned short s[4]; } pk;
      pk.s[0] = f2bf(w[0]); pk.s[1] = f2bf(w[1]); pk.s[2] = f2bf(w[2]); pk.s[3] = f2bf(w[3]);
      *(unsigned long long*)&Wbf[(t + 1) & 1][wd][wc] = pk.u;
    }

    // ---- compute tile t ----
    const float* ec = &encb[t & 3][0][0];
    const unsigned short* Wc = &Wbf[t & 1][0][0];
    {
      union { bf16x8 v; unsigned short u[8]; } bu;
#pragma unroll
      for (int j = 0; j < 8; ++j)
        bu.u[j] = f2bf(ec[(g * 8 + j) * T_SZ + n0 + tl]);
      bf16x8 a0 = *(const bf16x8*)&Wc[(0 * 16 + tl) * WBROW + g * 8];
      bf16x8 a1 = *(const bf16x8*)&Wc[(1 * 16 + tl) * WBROW + g * 8];
      bf16x8 a2 = *(const bf16x8*)&Wc[(2 * 16 + tl) * WBROW + g * 8];
      bf16x8 a3 = *(const bf16x8*)&Wc[(3 * 16 + tl) * WBROW + g * 8];
      acc0 = __builtin_amdgcn_mfma_f32_16x16x32_bf16(a0, bu.v, acc0, 0, 0, 0);
      acc1 = __builtin_amdgcn_mfma_f32_16x16x32_bf16(a1, bu.v, acc1, 0, 0, 0);
      acc2 = __builtin_amdgcn_mfma_f32_16x16x32_bf16(a2, bu.v, acc2, 0, 0, 0);
      acc3 = __builtin_amdgcn_mfma_f32_16x16x32_bf16(a3, bu.v, acc3, 0, 0, 0);
    }
    {
      // switch partial (exact f32): thread (t = tid&127, cg = tid>>7) covers 8 c's
      const int tsw = tid & 127, cg = tid >> 7;
      const float* wst = wswl + t * BK + cg * 8;
      const float* ep = ec + (cg * 8) * T_SZ + tsw;
      float s = 0.f;
#pragma unroll
      for (int c = 0; c < 8; ++c)
        s = fmaf(ep[c * T_SZ], wst[c], s);
      sw_acc += s;
    }
  }

  // ---------- switch reduce + bias + relu ----------
  swpart[tid] = sw_acc;
  __syncthreads();
  if (tid < T_SZ) {
    float s = swpart[tid] + swpart[tid + 128] + swpart[tid + 256] + swpart[tid + 384];
    s += bsw[0];
    attn[tid] = fmaxf(s, 0.f);
  }
  __syncthreads();

  // ---------- top-16 descending, ties -> lower index (wave 0) ----------
  if (tid < 64) {
    float v0 = attn[tid], v1 = attn[tid + 64];
#pragma unroll 1
    for (int r = 0; r < NEV; ++r) {
      float bv; int bi;
      if (v0 >= v1) { bv = v0; bi = tid; } else { bv = v1; bi = tid + 64; }
#pragma unroll
      for (int off = 32; off > 0; off >>= 1) {
        float ov = __shfl_xor(bv, off, 64);
        int   oi = __shfl_xor(bi, off, 64);
        if (ov > bv || (ov == bv && oi < bi)) { bv = ov; bi = oi; }
      }
      if (bi == tid) v0 = -__builtin_inff();
      if (bi == tid + 64) v1 = -__builtin_inff();
      if (tid == r) { topv[r] = bv; topi[r] = bi; }
    }
  }
  __syncthreads();

  // ---------- dump P (acc frags) to LDS, overlaying encb ----------
  float* Pl = (float*)&encb[0][0][0];  // [64][PLROW] f32 = 33.8 KB (encb dead)
  {
#pragma unroll
    for (int r = 0; r < 4; ++r) {
      Pl[(0 * 16 + 4 * g + r) * PLROW + n0 + tl] = acc0[r];
      Pl[(1 * 16 + 4 * g + r) * PLROW + n0 + tl] = acc1[r];
      Pl[(2 * 16 + 4 * g + r) * PLROW + n0 + tl] = acc2[r];
      Pl[(3 * 16 + 4 * g + r) * PLROW + n0 + tl] = acc3[r];
    }
  }
  __syncthreads();

  // ---------- scheduling: out[262144 + b*2048 + j*128 + t] ----------
  {
    float* os = out + (256 * NEV * CTX) + b * (NEV * T_SZ);
    int j  = tid >> 5;
    int t0 = (tid * 4) & 127;
    float tv = topv[j];
    int   ti = topi[j];
    float4 v;
    v.x = (t0 + 0 == ti) ? tv : 0.f;
    v.y = (t0 + 1 == ti) ? tv : 0.f;
    v.z = (t0 + 2 == ti) ? tv : 0.f;
    v.w = (t0 + 3 == ti) ? tv : 0.f;
    *(float4*)&os[tid * 4] = v;
  }
  // ---------- vecs: out[b*1024 + j*64 + d] = P[d][idx[j]] + b_vec[d] ----------
  {
    float* ov = out + b * (NEV * CTX);
#pragma unroll
    for (int s = 0; s < 2; ++s) {
      int o = s * NTHR + tid;
      int j = o >> 6, d = o & 63;
      ov[o] = Pl[d * PLROW + topi[j]] + bvec[d];
    }
  }
}

extern "C" void kernel_launch(void* const* d_in, const int* in_sizes, int n_in,
                              void* d_out, int out_size, void* d_ws, size_t ws_size,
                              hipStream_t stream) {
  const float* enc  = (const float*)d_in[0];
  const float* wvec = (const float*)d_in[1];
  const float* bvec = (const float*)d_in[2];
  const float* wsw  = (const float*)d_in[3];
  const float* bsw  = (const float*)d_in[4];
  float* o = (float*)d_out;
  (void)in_sizes; (void)n_in; (void)out_size; (void)d_ws; (void)ws_size;
  fused_sparsify<<<256, NTHR, 0, stream>>>(enc, wvec, bvec, wsw, bsw, o);
}

// Round 4
// 35.858 us; speedup vs baseline: 1.3357x; 1.3357x over previous
//
#include <hip/hip_runtime.h>
#include <hip/hip_bf16.h>

#define C_IN 1024
#define T_SZ 128
#define CTX 64
#define NEV 16
#define BK 64
#define NTILE 16     // C_IN / BK
#define NTHR 512
#define BROW 72      // bf16 row stride (144 B = 9*16: aligned, bank-uniform)
#define PLROW 132    // padded P dump row stride (f32 elems)

// arena layout (bytes)
#define BF_OFF 0                       // Bf: 2 * 128 * 72 * 2 = 36864
#define WB_OFF 36864                   // Wb: 2 * 64 * 72 * 2  = 18432
#define WS_OFF 55296                   // wswl: 1024 * 4       = 4096
#define SP_OFF 59392                   // swp:  8 * 128 * 4    = 4096
#define AT_OFF 63488                   // attn: 128 * 4        = 512
#define TV_OFF 64000                   // topv: 16 * 4
#define TI_OFF 64064                   // topi: 16 * 4
#define ARENA_SZ 64128

typedef short bf16x8 __attribute__((ext_vector_type(8)));
typedef float f32x4 __attribute__((ext_vector_type(4)));

__device__ __forceinline__ unsigned short f2bf(float f) {
  __hip_bfloat16 h = __float2bfloat16(f);
  return *(unsigned short*)&h;
}

#define BARRIER() do { \
  asm volatile("s_waitcnt lgkmcnt(0)" ::: "memory"); \
  __builtin_amdgcn_s_barrier(); \
} while (0)

// load enc tile kt slice (8 c x 2 t per thread, coalesced 512B/instr) + W tile slice
#define ISSUE(kt, ev, wv) do { \
  const float* _s = encB + (kt) * (BK * T_SZ) + cb0 * T_SZ + t0; \
  _Pragma("unroll") for (int _j = 0; _j < 8; ++_j) \
    ev[_j] = *(const float2*)(_s + _j * T_SZ); \
  const float* _w = wvec + wd * C_IN + (kt) * BK + wc; \
  wv[0] = *(const float4*)_w; \
  wv[1] = *(const float4*)(_w + 4); \
} while (0)

// switch partial (exact f32) + convert to bf16 + write B/W fragments to LDS
#define CONVERT(kt, ev, wv, buf) do { \
  const float* _wt = wswl + (kt) * BK + cb0; \
  union { bf16x8 v; unsigned short u[8]; } _p0, _p1, _pw; \
  _Pragma("unroll") for (int _j = 0; _j < 8; ++_j) { \
    sw0 = fmaf(ev[_j].x, _wt[_j], sw0); \
    sw1 = fmaf(ev[_j].y, _wt[_j], sw1); \
    _p0.u[_j] = f2bf(ev[_j].x); \
    _p1.u[_j] = f2bf(ev[_j].y); \
  } \
  *(bf16x8*)&Bf[((buf) * T_SZ + t0) * BROW + cb0] = _p0.v; \
  *(bf16x8*)&Bf[((buf) * T_SZ + t0 + 1) * BROW + cb0] = _p1.v; \
  _pw.u[0] = f2bf(wv[0].x); _pw.u[1] = f2bf(wv[0].y); \
  _pw.u[2] = f2bf(wv[0].z); _pw.u[3] = f2bf(wv[0].w); \
  _pw.u[4] = f2bf(wv[1].x); _pw.u[5] = f2bf(wv[1].y); \
  _pw.u[6] = f2bf(wv[1].z); _pw.u[7] = f2bf(wv[1].w); \
  *(bf16x8*)&Wb[((buf) * CTX + wd) * BROW + wc] = _pw.v; \
} while (0)

#define MFMA_TILE(buf) do { \
  _Pragma("unroll") for (int _ks = 0; _ks < 2; ++_ks) { \
    bf16x8 _bv = *(const bf16x8*)&Bf[((buf) * T_SZ + n0 + tl) * BROW + _ks * 32 + g * 8]; \
    bf16x8 _a0 = *(const bf16x8*)&Wb[((buf) * CTX +  0 + tl) * BROW + _ks * 32 + g * 8]; \
    bf16x8 _a1 = *(const bf16x8*)&Wb[((buf) * CTX + 16 + tl) * BROW + _ks * 32 + g * 8]; \
    bf16x8 _a2 = *(const bf16x8*)&Wb[((buf) * CTX + 32 + tl) * BROW + _ks * 32 + g * 8]; \
    bf16x8 _a3 = *(const bf16x8*)&Wb[((buf) * CTX + 48 + tl) * BROW + _ks * 32 + g * 8]; \
    acc0 = __builtin_amdgcn_mfma_f32_16x16x32_bf16(_a0, _bv, acc0, 0, 0, 0); \
    acc1 = __builtin_amdgcn_mfma_f32_16x16x32_bf16(_a1, _bv, acc1, 0, 0, 0); \
    acc2 = __builtin_amdgcn_mfma_f32_16x16x32_bf16(_a2, _bv, acc2, 0, 0, 0); \
    acc3 = __builtin_amdgcn_mfma_f32_16x16x32_bf16(_a3, _bv, acc3, 0, 0, 0); \
  } \
} while (0)

__global__ __launch_bounds__(NTHR, 1) void fused_sparsify(
    const float* __restrict__ enc,   // [256][1024][128] f32
    const float* __restrict__ wvec,  // [64][1024] f32
    const float* __restrict__ bvec,  // [64] f32
    const float* __restrict__ wsw,   // [1024] f32
    const float* __restrict__ bsw,   // [1] f32
    float* __restrict__ out)         // vecs [256*16*64] ++ sched [256*16*128], f32
{
  const int b    = blockIdx.x;
  const int tid  = threadIdx.x;
  const int lane = tid & 63;
  const int wid  = tid >> 6;   // wave 0..7
  const int g    = lane >> 4;  // k-group 0..3
  const int tl   = lane & 15;
  const int n0   = wid * 16;   // this wave's MFMA t-slice

  // staging geometry: wave = c-block of 8, lane = t-pair
  const int cb0 = wid * 8;     // c offset within tile
  const int t0  = 2 * lane;    // t pair
  const int wd  = tid >> 3;    // W row 0..63
  const int wc  = (tid & 7) * 8;

  __shared__ __align__(16) char arena[ARENA_SZ];
  unsigned short* Bf = (unsigned short*)(arena + BF_OFF);  // [2][128][BROW] bf16
  unsigned short* Wb = (unsigned short*)(arena + WB_OFF);  // [2][64][BROW] bf16
  float* wswl = (float*)(arena + WS_OFF);
  float* swp  = (float*)(arena + SP_OFF);                  // [8][128]
  float* attn = (float*)(arena + AT_OFF);
  float* topv = (float*)(arena + TV_OFF);
  int*   topi = (int*)(arena + TI_OFF);

  const float* encB = enc + (size_t)b * (C_IN * T_SZ);

  wswl[tid]       = wsw[tid];
  wswl[tid + 512] = wsw[tid + 512];

  f32x4 acc0 = {0.f, 0.f, 0.f, 0.f};
  f32x4 acc1 = acc0, acc2 = acc0, acc3 = acc0;
  float sw0 = 0.f, sw1 = 0.f;

  float2 evA[8], evB[8];
  float4 wvA[2], wvB[2];

  // ---------- prologue ----------
  ISSUE(0, evA, wvA);
  ISSUE(1, evB, wvB);
  BARRIER();                 // publish wswl (reg loads stay in flight)
  CONVERT(0, evA, wvA, 0);
  BARRIER();                 // publish Bf[0], Wb[0]

  // ---------- main loop: depth-2 reg prefetch, 1 raw barrier per tile ----------
#pragma unroll 1
  for (int t = 0; t < NTILE; t += 2) {
    if (t + 2 < NTILE) ISSUE(t + 2, evA, wvA);
    MFMA_TILE(0);
    CONVERT(t + 1, evB, wvB, 1);           // t+1 <= 15 always
    BARRIER();
    if (t + 3 < NTILE) ISSUE(t + 3, evB, wvB);
    MFMA_TILE(1);
    if (t + 2 < NTILE) CONVERT(t + 2, evA, wvA, 0);
    BARRIER();
  }

  // ---------- epilogue: P dump (overlay Bf region, dead now) + switch partials ----------
  float* Pl = (float*)(arena + BF_OFF);    // [64][PLROW] f32 = 33792 B <= 36864
#pragma unroll
  for (int r = 0; r < 4; ++r) {
    Pl[( 0 + 4 * g + r) * PLROW + n0 + tl] = acc0[r];
    Pl[(16 + 4 * g + r) * PLROW + n0 + tl] = acc1[r];
    Pl[(32 + 4 * g + r) * PLROW + n0 + tl] = acc2[r];
    Pl[(48 + 4 * g + r) * PLROW + n0 + tl] = acc3[r];
  }
  swp[wid * T_SZ + t0]     = sw0;
  swp[wid * T_SZ + t0 + 1] = sw1;
  __syncthreads();

  if (tid < T_SZ) {
    float s = 0.f;
#pragma unroll
    for (int k = 0; k < 8; ++k) s += swp[k * T_SZ + tid];
    attn[tid] = fmaxf(s + bsw[0], 0.f);
  }
  __syncthreads();

  // ---------- top-16 descending, ties -> lower index (wave 0) ----------
  if (tid < 64) {
    float v0 = attn[tid], v1 = attn[tid + 64];
#pragma unroll 1
    for (int r = 0; r < NEV; ++r) {
      float bv; int bi;
      if (v0 >= v1) { bv = v0; bi = tid; } else { bv = v1; bi = tid + 64; }
#pragma unroll
      for (int off = 32; off > 0; off >>= 1) {
        float ov = __shfl_xor(bv, off, 64);
        int   oi = __shfl_xor(bi, off, 64);
        if (ov > bv || (ov == bv && oi < bi)) { bv = ov; bi = oi; }
      }
      if (bi == tid) v0 = -__builtin_inff();
      if (bi == tid + 64) v1 = -__builtin_inff();
      if (tid == r) { topv[r] = bv; topi[r] = bi; }
    }
  }
  __syncthreads();

  // ---------- scheduling: out[262144 + b*2048 + j*128 + t] ----------
  {
    float* os = out + (256 * NEV * CTX) + b * (NEV * T_SZ);
    int j  = tid >> 5;
    int tt = (tid * 4) & 127;
    float tv = topv[j];
    int   ti = topi[j];
    float4 v;
    v.x = (tt + 0 == ti) ? tv : 0.f;
    v.y = (tt + 1 == ti) ? tv : 0.f;
    v.z = (tt + 2 == ti) ? tv : 0.f;
    v.w = (tt + 3 == ti) ? tv : 0.f;
    *(float4*)&os[tid * 4] = v;
  }
  // ---------- vecs: out[b*1024 + j*64 + d] = P[d][idx[j]] + b_vec[d] ----------
  {
    float* ov = out + b * (NEV * CTX);
#pragma unroll
    for (int s = 0; s < 2; ++s) {
      int o = s * NTHR + tid;
      int j = o >> 6, d = o & 63;
      ov[o] = Pl[d * PLROW + topi[j]] + bvec[d];
    }
  }
}

extern "C" void kernel_launch(void* const* d_in, const int* in_sizes, int n_in,
                              void* d_out, int out_size, void* d_ws, size_t ws_size,
                              hipStream_t stream) {
  const float* enc  = (const float*)d_in[0];
  const float* wvec = (const float*)d_in[1];
  const float* bvec = (const float*)d_in[2];
  const float* wsw  = (const float*)d_in[3];
  const float* bsw  = (const float*)d_in[4];
  float* o = (float*)d_out;
  (void)in_sizes; (void)n_in; (void)out_size; (void)d_ws; (void)ws_size;
  fused_sparsify<<<256, NTHR, 0, stream>>>(enc, wvec, bvec, wsw, bsw, o);
}